// Round 8
// baseline (269.003 us; speedup 1.0000x reference)
//
#include <hip/hip_runtime.h>

// GGNN message passing, round 8: prep_all restructured for 16-deep outstanding
// loads (r7 post-mortem: VGPR_Count=32 batched loads ~4 deep -> 1.18 TB/s;
// 4-deep x 16B x 32 waves/CU / 375ns = 1.4 TB/s, matches. Preloading into
// int4 v[16] register arrays lifts in-flight depth 4x). Main kernel unchanged
// (proven r5-r7, absmax 1.0).
//
//   adj in {0..3}. Planes: B0 = bit0(adj), B1 = bit1(adj), T = B0&B1.
//   P0 = B0@H, P1 = B1@H, PT = T@H, PA[e] = sum_j h[j][e]  (per batch)
//   m = P0(M1-M0)^T + P1(M2-M0)^T + PT(M0-M1-M2+M3)^T + PA M0^T + bias
//   (out-direction: same with adj^T and Mout.)

namespace {

typedef unsigned int   u32;
typedef unsigned short u16;
typedef unsigned char  u8;
typedef __attribute__((ext_vector_type(8))) short bf16x8;
typedef __attribute__((ext_vector_type(4))) float f32x4;

constexpr int NN = 1024;

__device__ inline u16 f2bf(float x) {                  // f32 -> bf16 bits, RNE
    u32 u = __float_as_uint(x);
    return (u16)((u + 0x7FFFu + ((u >> 16) & 1u)) >> 16);
}
// z bits 0,2 = indicators (rest masked) -> u32 of 2 bf16 {0,1}. Proven r3-r7.
__device__ inline u32 oh2(u32 z) {
    return ((z & 1u) | ((z & 4u) << 14)) * 0x3F80u;
}

// ------------------------------------------------ K1: prep_all (one dispatch)
// blocks 0..2047   : pack one 64x256 adj tile -> adjP (row words) + adjPT (col)
// blocks 2048..2303: prep_h, 128 j-rows each -> Hws bf16 H^T + PApart
// block  2304      : M planes -> Mws bf16 [dir][4][64][64]
__global__ __launch_bounds__(256) void prep_all(
    const int* __restrict__ adj, const float* __restrict__ h,
    const float* __restrict__ Min, const float* __restrict__ Mout,
    u32* __restrict__ adjP, u32* __restrict__ adjPT,
    u16* __restrict__ Hws, float* __restrict__ PApart, u16* __restrict__ Mws)
{
    __shared__ __align__(16) char sbuf[19456];
    const int t = threadIdx.x;
    const int bid = blockIdx.x;

    if (bid < 2048) {
        // ---- pack tile (b, It, Jt, s): rows It*256+s*64..+64, cols Jt*256..+256
        u8* ldsR = (u8*)sbuf;          // [64 rows][64 c4] bytes (byte = 4 codes)
        u8* ldsC = (u8*)sbuf + 4096;   // [64 c4][68 rows] transposed
        const int b = bid >> 6, It = (bid >> 4) & 3, Jt = (bid >> 2) & 3, s = bid & 3;
        const int* base = adj + ((size_t)b << 20)
                        + (size_t)(It * 256 + s * 64) * NN + Jt * 256;

        // PRELOAD: 16 independent int4 loads in flight before any consumption
        int4 v[16];
        #pragma unroll
        for (int k = 0; k < 16; ++k) {          // wave reads 1 KB contiguous
            int f = k * 256 + t;
            int row = f >> 6, c4 = f & 63;
            v[k] = *(const int4*)(base + row * NN + c4 * 4);
        }
        #pragma unroll
        for (int k = 0; k < 16; ++k) {
            int f = k * 256 + t;
            int row = f >> 6, c4 = f & 63;
            u8 byte = (u8)((v[k].x & 3) | ((v[k].y & 3) << 2)
                         | ((v[k].z & 3) << 4) | ((v[k].w & 3) << 6));
            ldsR[row * 64 + c4] = byte;
            ldsC[c4 * 68 + row] = byte;
        }
        __syncthreads();

        // row words: one uint4 per thread = 64 codes
        {
            int row = t >> 2, seg = t & 3;
            uint4 wv = *(const uint4*)&ldsR[row * 64 + seg * 16];
            u32* op = adjP + (((((size_t)b * 4 + Jt) * 16 + It * 4 + s) * 4 + seg) * 64 + row) * 4;
            *(uint4*)op = wv;
        }
        // col words: thread t owns column c = t; 4 words of 16 rows
        {
            int c4 = t >> 2, bp = (t & 3) * 2;
            int sc = t >> 6, il = t & 63;
            u32 o[4];
            #pragma unroll
            for (int jj = 0; jj < 4; ++jj) {
                u32 acc = 0;
                #pragma unroll
                for (int m4 = 0; m4 < 4; ++m4) {
                    u32 r = *(const u32*)&ldsC[c4 * 68 + jj * 16 + m4 * 4];
                    #pragma unroll
                    for (int m = 0; m < 4; ++m)
                        acc |= ((r >> (8 * m + bp)) & 3u) << (2 * (m4 * 4 + m));
                }
                o[jj] = acc;
            }
            u32* op2 = adjPT + (((((size_t)b * 4 + It) * 16 + Jt * 4 + sc) * 4 + s) * 64 + il) * 4;
            *(uint4*)op2 = make_uint4(o[0], o[1], o[2], o[3]);
        }
        return;
    }

    if (bid < 2304) {
        // ---- prep_h: idx -> (b, jc, half); 128 j-rows
        u16 (*hl)[72] = (u16(*)[72])sbuf;            // 18432 B
        float* red = (float*)(sbuf + 18432);         // [4][64]
        const int idx = bid - 2048;
        const int b = idx >> 3, jc = (idx >> 1) & 3, half = idx & 1;
        const float* hb = h + ((size_t)b * NN + jc * 256 + half * 128) * 64;

        float4 v[8];                                 // PRELOAD 8 deep
        #pragma unroll
        for (int k = 0; k < 8; ++k) {
            int f = k * 256 + t;
            int j = f >> 4, e4 = (f & 15) * 4;
            v[k] = *(const float4*)(hb + (size_t)j * 64 + e4);
        }
        #pragma unroll
        for (int k = 0; k < 8; ++k) {
            int f = k * 256 + t;
            int j = f >> 4, e4 = (f & 15) * 4;
            *(u32*)&hl[j][e4]     = (u32)f2bf(v[k].x) | ((u32)f2bf(v[k].y) << 16);
            *(u32*)&hl[j][e4 + 2] = (u32)f2bf(v[k].z) | ((u32)f2bf(v[k].w) << 16);
        }
        __syncthreads();
        u16* ob = Hws + (size_t)(b * 4 + jc) * 16384 + (size_t)half * 16 * 64 * 8;
        const int e = t & 63;
        float psum = 0.f;
        #pragma unroll
        for (int k = 0; k < 4; ++k) {
            int u = k * 4 + (t >> 6);               // local octet 0..15
            u16 x0 = hl[u * 8 + 0][e], x1 = hl[u * 8 + 1][e];
            u16 x2 = hl[u * 8 + 2][e], x3 = hl[u * 8 + 3][e];
            u16 x4 = hl[u * 8 + 4][e], x5 = hl[u * 8 + 5][e];
            u16 x6 = hl[u * 8 + 6][e], x7 = hl[u * 8 + 7][e];
            psum += __uint_as_float((u32)x0 << 16) + __uint_as_float((u32)x1 << 16)
                  + __uint_as_float((u32)x2 << 16) + __uint_as_float((u32)x3 << 16)
                  + __uint_as_float((u32)x4 << 16) + __uint_as_float((u32)x5 << 16)
                  + __uint_as_float((u32)x6 << 16) + __uint_as_float((u32)x7 << 16);
            u32 p0 = (u32)x0 | ((u32)x1 << 16), p1 = (u32)x2 | ((u32)x3 << 16);
            u32 p2 = (u32)x4 | ((u32)x5 << 16), p3 = (u32)x6 | ((u32)x7 << 16);
            *(uint4*)(ob + (size_t)(u * 64 + e) * 8) = make_uint4(p0, p1, p2, p3);
        }
        red[(t >> 6) * 64 + e] = psum;
        __syncthreads();
        if (t < 64) {
            float sum = red[t] + red[64 + t] + red[128 + t] + red[192 + t];
            PApart[(size_t)((jc * 2 + half) * 32 + b) * 64 + t] = sum;
        }
        return;
    }

    // ---- M planes: {M1-M0, M2-M0, M0-M1-M2+M3, M0} per dir
    for (int i = t; i < 8192; i += 256) {
        const float* M = (i < 4096) ? Min : Mout;
        int idx = i & 4095;
        float m0 = M[idx], m1 = M[4096 + idx], m2 = M[8192 + idx], m3 = M[12288 + idx];
        u16* o = Mws + (size_t)(i >> 12) * 16384;
        o[idx]         = f2bf(m1 - m0);
        o[4096 + idx]  = f2bf(m2 - m0);
        o[8192 + idx]  = f2bf(m0 - m1 - m2 + m3);
        o[12288 + idx] = f2bf(m0);
    }
}

// ------------------------------------------------------------------ K2: main
__global__ __launch_bounds__(256) void ggnn_main(
    const u32* __restrict__ adjP, const u32* __restrict__ adjPT,
    const u16* __restrict__ Hws, const u16* __restrict__ Mws,
    const float* __restrict__ PApart, const float* __restrict__ bias,
    float* __restrict__ out)
{
    __shared__ u16 Sb[16][16][72];   // per-wave slots w*4+p (p=3 -> PA plane)

    const int t = threadIdx.x;
    const int w = t >> 6;
    const int ln = t & 15, qd = (t & 63) >> 4, qd2 = qd >> 1;
    const int shamt = (qd & 1) * 16;
    const int bid = blockIdx.x;
    const int dir = bid & 1;                 // interleave dirs: share H tile in L2
    const int r2 = bid >> 1;
    const int b = r2 >> 4, it = r2 & 15;

    const u32* Adir = dir ? adjPT : adjP;
    f32x4 acc[3][4];
    #pragma unroll
    for (int p = 0; p < 3; ++p)
        #pragma unroll
        for (int nt = 0; nt < 4; ++nt) acc[p][nt] = (f32x4){0.f, 0.f, 0.f, 0.f};

    for (int jc = 0; jc < 4; ++jc) {
        const u32* at = Adir + (size_t)((b * 4 + jc) * 16 + it) * 1024;
        const u16* ht = Hws + (size_t)(b * 4 + jc) * 16384;

        uint4 Ar[4];
        #pragma unroll
        for (int u = 0; u < 4; ++u)
            Ar[u] = *(const uint4*)(at + (u * 64 + w * 16 + ln) * 4);

        #pragma unroll
        for (int ks = 0; ks < 8; ++ks) {
            bf16x8 bf[4];
            #pragma unroll
            for (int nt = 0; nt < 4; ++nt)
                bf[nt] = *(const bf16x8*)(ht + (size_t)((ks * 4 + qd) * 64 + nt * 16 + ln) * 8);

            uint4 Q = Ar[ks >> 1];
            u32 a = (ks & 1) ? (qd2 ? Q.w : Q.z) : (qd2 ? Q.y : Q.x);
            u32 f = (a >> shamt) & 0xFFFFu;
            u32 x0 = f & 0x5555u;
            u32 x1 = (f >> 1) & 0x5555u;
            u32 xt = x0 & x1;

            union { u32 u[4]; bf16x8 v; } A0, A1, AT;
            #pragma unroll
            for (int wd = 0; wd < 4; ++wd) {
                A0.u[wd] = oh2(x0 >> (4 * wd));
                A1.u[wd] = oh2(x1 >> (4 * wd));
                AT.u[wd] = oh2(xt >> (4 * wd));
            }
            #pragma unroll
            for (int nt = 0; nt < 4; ++nt) {
                acc[0][nt] = __builtin_amdgcn_mfma_f32_16x16x32_bf16(A0.v, bf[nt], acc[0][nt], 0, 0, 0);
                acc[1][nt] = __builtin_amdgcn_mfma_f32_16x16x32_bf16(A1.v, bf[nt], acc[1][nt], 0, 0, 0);
                acc[2][nt] = __builtin_amdgcn_mfma_f32_16x16x32_bf16(AT.v, bf[nt], acc[2][nt], 0, 0, 0);
            }
        }
    }

    // P (C-layout regs) -> LDS bf16 per-wave slots; wave-internal, no barrier
    #pragma unroll
    for (int p = 0; p < 3; ++p)
        #pragma unroll
        for (int nt = 0; nt < 4; ++nt)
            #pragma unroll
            for (int r = 0; r < 4; ++r)
                Sb[w * 4 + p][qd * 4 + r][nt * 16 + ln] = f2bf(acc[p][nt][r]);

    // plane 3: S3[i][e] = PA[e] (sum of 8 per-chunk partials)
    {
        const int lane64 = t & 63;
        float paf = 0.f;
        #pragma unroll
        for (int jcp = 0; jcp < 8; ++jcp)
            paf += PApart[(size_t)(jcp * 32 + b) * 64 + lane64];
        u16 pab = f2bf(paf);
        #pragma unroll
        for (int i = 0; i < 16; ++i)
            Sb[w * 4 + 3][i][lane64] = pab;
    }

    const int dofs = dir * 64;
    f32x4 acc2[4];
    #pragma unroll
    for (int dt = 0; dt < 4; ++dt) {
        float v = bias[dofs + dt * 16 + ln];
        acc2[dt] = (f32x4){v, v, v, v};
    }
    const u16* Mb = Mws + (size_t)dir * 16384;   // [4][64][64]
    #pragma unroll
    for (int p = 0; p < 4; ++p) {
        #pragma unroll
        for (int ks2 = 0; ks2 < 2; ++ks2) {
            bf16x8 af = *(const bf16x8*)&Sb[w * 4 + p][ln][ks2 * 32 + qd * 8];
            #pragma unroll
            for (int dt = 0; dt < 4; ++dt) {
                bf16x8 mf = *(const bf16x8*)(Mb + (size_t)(p * 64 + dt * 16 + ln) * 64
                                             + ks2 * 32 + qd * 8);
                acc2[dt] = __builtin_amdgcn_mfma_f32_16x16x32_bf16(af, mf, acc2[dt], 0, 0, 0);
            }
        }
    }
    #pragma unroll
    for (int dt = 0; dt < 4; ++dt)
        #pragma unroll
        for (int r = 0; r < 4; ++r)
            out[((size_t)b * NN + it * 64 + w * 16 + qd * 4 + r) * 128
                + dofs + dt * 16 + ln] = acc2[dt][r];
}

} // namespace

extern "C" void kernel_launch(void* const* d_in, const int* in_sizes, int n_in,
                              void* d_out, int out_size, void* d_ws, size_t ws_size,
                              hipStream_t stream) {
    (void)in_sizes; (void)n_in; (void)out_size; (void)ws_size;
    const float* h    = (const float*)d_in[0];   // [32,1024,64] f32
    const int*   adj  = (const int*)d_in[1];     // [32,1024,1024] i32
    const float* Min  = (const float*)d_in[2];   // [4,64,64] f32
    const float* Mout = (const float*)d_in[3];   // [4,64,64] f32
    const float* bias = (const float*)d_in[4];   // [128] f32
    float* out = (float*)d_out;                  // [32,1024,128] f32

    char* ws = (char*)d_ws;
    u32* adjP     = (u32*)(ws + 0);              // 8 MB
    u32* adjPT    = (u32*)(ws + 8388608);        // 8 MB
    u16* Hws      = (u16*)(ws + 16777216);       // 4 MB
    float* PApart = (float*)(ws + 20971520);     // 64 KB [8][32][64]
    u16* Mws      = (u16*)(ws + 21037056);       // 64 KB [2][4][64][64]

    prep_all<<<2305, 256, 0, stream>>>(adj, h, Min, Mout, adjP, adjPT, Hws, PApart, Mws);
    ggnn_main<<<1024, 256, 0, stream>>>(adjP, adjPT, Hws, Mws, PApart, bias, out);
}